// Round 6
// baseline (64.263 us; speedup 1.0000x reference)
//
#include <hip/hip_runtime.h>
#include <hip/hip_bf16.h>

#define B 16
#define N 10000
#define D 64
#define R 64
#define H 512
#define K 32
#define NBLK ((N + 255) / 256)       // 40  (k_norm grid)
#define NRBF ((N + 127) / 128)       // 79  (k_rbf grid: 128 n per block)
#define NBUCK 4096

typedef unsigned long long ull;

// ---------- ws layout (bytes) ----------
// oidx   : B*K int     @ 0        (2048)
// ow     : B*K f32     @ 2048     (2048)
// tm     : B*K*D f32   @ 4096     (131072)
// nm2    : B*K f32     @ 135168   (-0.5*||mean||^2)
// part   : B*NRBF f32  @ 137216   (5056 -> pad 5120)
// rp     : B*H f32     @ 142336   (b1 + r_b @ W1[:, :R].T)

// ---------------- kernel 1: exact top-K set + r_part ----------------
__global__ __launch_bounds__(1024) void k_topk(const float* __restrict__ e,
                                               const float* __restrict__ rE,
                                               const float* __restrict__ W1,
                                               const float* __restrict__ b1,
                                               int* __restrict__ oidx,
                                               float* __restrict__ ow,
                                               float* __restrict__ rp) {
    const int b = blockIdx.x, tid = threadIdx.x;
    __shared__ unsigned hist[NBUCK];
    __shared__ ull cand[1024];
    __shared__ float rEs[R];
    __shared__ unsigned cnt;
    __shared__ int tsh;

    #pragma unroll
    for (int i = 0; i < NBUCK / 1024; ++i) hist[tid + i * 1024] = 0;
    if (tid == 0) cnt = 0;
    if (tid < R) rEs[tid] = rE[b * R + tid];

    ull keys[10];
    int bkt[10];
    #pragma unroll
    for (int i = 0; i < 10; ++i) {
        const int n = tid + i * 1024;
        keys[i] = 0ull; bkt[i] = -1;
        if (n < N) {
            const float v = e[b * N + n];
            keys[i] = ((ull)__float_as_uint(v) << 32) |
                      (unsigned)(0xFFFFFFFFu - (unsigned)n);
            int bu = (int)(v * (float)NBUCK);
            bkt[i] = bu > NBUCK - 1 ? NBUCK - 1 : (bu < 0 ? 0 : bu);
        }
    }
    __syncthreads();
    #pragma unroll
    for (int i = 0; i < 10; ++i) if (bkt[i] >= 0) atomicAdd(&hist[bkt[i]], 1u);
    __syncthreads();

    // wave 0: parallel suffix scan from the top, 64 buckets per step
    if (tid < 64) {
        unsigned acc = 0;
        for (int w = 0; w < NBUCK / 64; ++w) {
            const int j = NBUCK - 1 - (w * 64 + tid);
            unsigned p = hist[j];
            #pragma unroll
            for (int off = 1; off < 64; off <<= 1) {
                unsigned o = __shfl_up(p, off, 64);
                if (tid >= off) p += o;
            }
            const ull mask = __ballot(acc + p >= K);
            if (mask) {
                if (tid == 0) {
                    const int l0 = __ffsll((long long)mask) - 1;
                    tsh = NBUCK - 1 - (w * 64 + l0);
                }
                break;
            }
            acc += (unsigned)__shfl((int)p, 63, 64);
        }
    }
    __syncthreads();
    const int t = tsh;

    #pragma unroll
    for (int i = 0; i < 10; ++i)
        if (bkt[i] >= t) {
            unsigned p = atomicAdd(&cnt, 1u);
            if (p < 1024u) cand[p] = keys[i];
        }
    __syncthreads();

    const unsigned C = cnt < 1024u ? cnt : 1024u;
    if (tid < (int)C) {
        const ull mine = cand[tid];
        int rank = 0;
        for (unsigned j = 0; j < C; ++j) rank += (cand[j] > mine);
        if (rank < K) {
            oidx[b * K + rank] = (int)(0xFFFFFFFFu - (unsigned)(mine & 0xFFFFFFFFu));
            ow[b * K + rank] = __uint_as_float((unsigned)(mine >> 32));
        }
    }

    // r_part tail (independent of selection; rEs was written pre-barrier)
    if (tid < H) {
        const float4* w = (const float4*)(W1 + tid * (R + D));  // cols 0..R
        float acc = b1[tid];
        #pragma unroll
        for (int i = 0; i < R / 4; ++i) {
            const float4 wv = w[i];
            acc += wv.x * rEs[4 * i] + wv.y * rEs[4 * i + 1] +
                   wv.z * rEs[4 * i + 2] + wv.w * rEs[4 * i + 3];
        }
        rp[b * H + tid] = acc;
    }
}

// ---------------- kernel 2: MLP on selected rows (2 pairs/block) ----------------
__global__ __launch_bounds__(512) void k_means(
        const float* __restrict__ sup, const float* __restrict__ W1,
        const float* __restrict__ W2, const float* __restrict__ b2,
        const int* __restrict__ oidx, const float* __restrict__ rp,
        float* __restrict__ tm, float* __restrict__ nm2) {
    const int b = blockIdx.x >> 4, pr = blockIdx.x & 15;
    const int gk = b * K + pr * 2;
    const int tid = threadIdx.x;
    __shared__ float sA[D], sB[D];
    __shared__ float hA[H], hB[H];
    __shared__ float partA[512], partB[512];

    const int id0 = oidx[gk], id1 = oidx[gk + 1];
    if (tid < D) sA[tid] = sup[id0 * D + tid];
    else if (tid < 2 * D) sB[tid - D] = sup[id1 * D + (tid - D)];
    __syncthreads();

    {   // phase 1: one h-row per thread, weight row read once for both pairs
        const float4* w = (const float4*)(W1 + tid * (R + D) + R);
        float a0 = rp[b * H + tid], a1 = a0;
        #pragma unroll
        for (int i = 0; i < D / 4; ++i) {
            const float4 wv = w[i];
            a0 += wv.x * sA[4 * i] + wv.y * sA[4 * i + 1] +
                  wv.z * sA[4 * i + 2] + wv.w * sA[4 * i + 3];
            a1 += wv.x * sB[4 * i] + wv.y * sB[4 * i + 1] +
                  wv.z * sB[4 * i + 2] + wv.w * sB[4 * i + 3];
        }
        hA[tid] = fmaxf(a0, 0.f);
        hB[tid] = fmaxf(a1, 0.f);
    }
    __syncthreads();

    {   // phase 2: d = tid&63, 8 chunks of 64 over H
        const int d = tid & 63, ch = tid >> 6;
        const float4* w2 = (const float4*)(W2 + d * H + ch * 64);
        float a0 = 0.f, a1 = 0.f;
        #pragma unroll
        for (int i = 0; i < 16; ++i) {
            const float4 wv = w2[i];
            const int hb = ch * 64 + 4 * i;
            a0 += wv.x * hA[hb] + wv.y * hA[hb + 1] + wv.z * hA[hb + 2] + wv.w * hA[hb + 3];
            a1 += wv.x * hB[hb] + wv.y * hB[hb + 1] + wv.z * hB[hb + 2] + wv.w * hB[hb + 3];
        }
        partA[tid] = a0;
        partB[tid] = a1;
    }
    __syncthreads();

    if (tid < 128) {            // wave 0 -> pair 0, wave 1 -> pair 1
        const int d = tid & 63, w = tid >> 6;
        const float* part = w == 0 ? partA : partB;
        float m = b2[d];
        #pragma unroll
        for (int c = 0; c < 8; ++c) m += part[c * 64 + d];
        tm[(gk + w) * D + d] = m;
        float sq = m * m;
        #pragma unroll
        for (int off = 32; off > 0; off >>= 1) sq += __shfl_down(sq, off, 64);
        if (d == 0) nm2[gk + w] = -0.5f * sq;
    }
}

// ---------------- kernel 3: RBF, K-split x2, tm staged in LDS ----------------
// block = 128 n x 2 k-halves (256 thr). tm[b] tile (8KB) in LDS; inner reads
// are wave-uniform ds_read_b128 (pure broadcast). acc[16] chains give ILP 16;
// 1264 blocks give ~5 waves/SIMD of TLP.
__global__ __launch_bounds__(256) void k_rbf(
        const float* __restrict__ sup, const float* __restrict__ tm,
        const float* __restrict__ nm2, const float* __restrict__ ow,
        float* __restrict__ out, float* __restrict__ part) {
    const int b = blockIdx.y;
    const int tid = threadIdx.x;
    const int nloc = tid & 127;
    const int kb = (tid >> 7) * 16;           // k-half base: 0 or 16
    const int n = blockIdx.x * 128 + nloc;
    __shared__ float4 stm[K * 16];            // 8KB
    __shared__ float red[256];
    __shared__ float sw[K], snm2[K];
    __shared__ float wpart[2];

    const float4* tm4 = (const float4*)(tm + b * K * D);
    stm[tid] = tm4[tid];
    stm[tid + 256] = tm4[tid + 256];
    if (tid < K) { sw[tid] = ow[b * K + tid]; snm2[tid] = nm2[b * K + tid]; }
    __syncthreads();

    const int nc = n < N ? n : N - 1;         // clamp: tail lanes compute, zeroed later
    const float4* sp = (const float4*)(sup + nc * D);

    float acc[16];
    #pragma unroll
    for (int i = 0; i < 16; ++i) acc[i] = 0.f;
    float s2 = 0.f;

    #pragma unroll
    for (int dc = 0; dc < 4; ++dc) {
        const float4 s0 = sp[dc * 4 + 0];
        const float4 s1 = sp[dc * 4 + 1];
        const float4 s2v = sp[dc * 4 + 2];
        const float4 s3 = sp[dc * 4 + 3];
        s2 += s0.x * s0.x + s0.y * s0.y + s0.z * s0.z + s0.w * s0.w
            + s1.x * s1.x + s1.y * s1.y + s1.z * s1.z + s1.w * s1.w
            + s2v.x * s2v.x + s2v.y * s2v.y + s2v.z * s2v.z + s2v.w * s2v.w
            + s3.x * s3.x + s3.y * s3.y + s3.z * s3.z + s3.w * s3.w;
        #pragma unroll
        for (int kk = 0; kk < 16; ++kk) {
            const float4* mp = &stm[(kb + kk) * 16 + dc * 4];
            const float4 m0 = mp[0], m1 = mp[1], m2 = mp[2], m3 = mp[3];
            acc[kk] += s0.x * m0.x + s0.y * m0.y + s0.z * m0.z + s0.w * m0.w
                     + s1.x * m1.x + s1.y * m1.y + s1.z * m1.z + s1.w * m1.w
                     + s2v.x * m2.x + s2v.y * m2.y + s2v.z * m2.z + s2v.w * m2.w
                     + s3.x * m3.x + s3.y * m3.y + s3.z * m3.z + s3.w * m3.w;
        }
    }

    const float ns2 = -0.5f * s2;
    float total = 0.f;
    #pragma unroll
    for (int kk = 0; kk < 16; ++kk)
        total += sw[kb + kk] * __expf(ns2 + snm2[kb + kk] + acc[kk]);
    if (n >= N) total = 0.f;
    red[tid] = total;
    __syncthreads();

    float full = 0.f;
    if (tid < 128) {
        full = red[tid] + red[tid + 128];     // combine the two k-halves
        if (n < N) out[b * N + n] = full;
    }
    // block partial: waves 0,1 hold `full`
    float v = full;
    #pragma unroll
    for (int off = 32; off > 0; off >>= 1) v += __shfl_down(v, off, 64);
    if (tid < 128 && (tid & 63) == 0) wpart[tid >> 6] = v;
    __syncthreads();
    if (tid == 0) part[b * NRBF + blockIdx.x] = wpart[0] + wpart[1];
}

// ---------------- kernel 4: normalize ----------------
__global__ void k_norm(float* __restrict__ out, const float* __restrict__ part) {
    const int b = blockIdx.y;
    const int n = blockIdx.x * 256 + threadIdx.x;
    const int tid = threadIdx.x;
    __shared__ float sdiv;
    if (tid < 64) {
        float v = (tid < NRBF) ? part[b * NRBF + tid] : 0.f;
        if (tid + 64 < NRBF) v += part[b * NRBF + tid + 64];
        #pragma unroll
        for (int off = 32; off > 0; off >>= 1) v += __shfl_down(v, off, 64);
        if (tid == 0) sdiv = 1.f / (v + 1e-10f);
    }
    __syncthreads();
    if (n < N) out[b * N + n] *= sdiv;
}

extern "C" void kernel_launch(void* const* d_in, const int* in_sizes, int n_in,
                              void* d_out, int out_size, void* d_ws, size_t ws_size,
                              hipStream_t stream) {
    const float* e   = (const float*)d_in[0];
    const float* rE  = (const float*)d_in[1];
    const float* sup = (const float*)d_in[2];
    const float* W1  = (const float*)d_in[3];
    const float* b1  = (const float*)d_in[4];
    const float* W2  = (const float*)d_in[5];
    const float* b2  = (const float*)d_in[6];
    float* out = (float*)d_out;

    char* ws = (char*)d_ws;
    int*   oidx = (int*)(ws + 0);
    float* ow   = (float*)(ws + 2048);
    float* tm   = (float*)(ws + 4096);
    float* nm2  = (float*)(ws + 135168);
    float* part = (float*)(ws + 137216);
    float* rp   = (float*)(ws + 142336);

    hipLaunchKernelGGL(k_topk, dim3(B), dim3(1024), 0, stream,
                       e, rE, W1, b1, oidx, ow, rp);
    hipLaunchKernelGGL(k_means, dim3(B * 16), dim3(512), 0, stream,
                       sup, W1, W2, b2, oidx, rp, tm, nm2);
    hipLaunchKernelGGL(k_rbf, dim3(NRBF, B), dim3(256), 0, stream,
                       sup, tm, nm2, ow, out, part);
    hipLaunchKernelGGL(k_norm, dim3(NBLK, B), dim3(256), 0, stream, out, part);
}